// Round 12
// baseline (151.377 us; speedup 1.0000x reference)
//
#include <hip/hip_runtime.h>
#include <hip/hip_fp16.h>
#include <math.h>

// H = 64, N = 50000 nodes, E = 1.6M edges.
// d_out = [ new_mean (N*64) | new_std (N*64) | total_kl (1) ]
//
// Pipeline:
//   1. k_transform_hist: MFMA h_m = mean@Wm, h_v = (std^2)@Ws -> pk (fp16
//      chunk layout, 256 B/node) + fused grid-stride 1564-bucket histogram
//      of dst>>5.
//   2. k_scan_kl: block 0 = two-round 1024-wide exclusive scan of bucket
//      counts (-> sbase, bcur); block 1 = KL reduction.
//   3. k_bucket_scatter: two-pass, 16384 edges per block (512 thr): pass A
//      counts in LDS, one cursor reservation per bucket, pass B re-reads and
//      writes ~10-edge contiguous runs.
//   4. k_sub_agg: one block per bucket (32 nodes, ~1024 records, 256 thr,
//      4 waves, ~6.7 KB LDS -> 8 blocks/CU, ALL blocks resident); counting
//      sort into LDS, wave-per-node register reduce, fused epilogue.
//
// Lesson log: r10 LDS-atomic accumulation = 17x regression (sort + register
// reduce is right); r5 forced occupancy = spills (never cap VGPR below live
// set); r11 782-block agg left a 3.05-round grid tail.
//
// ws: bcnt[2048] | sbase[2080] | bcur[2048] | dlo uchar[E] | esrcw uint[E]
//     | pk uint[n*64]   (~21 MB)

#define NB3  1564                // buckets (dst >> 5), 32 nodes each
#define SCAP 1536                // max records/bucket (mean 1024, ~16 sigma)
#define SBLK 16384               // edges per scatter block

typedef _Float16 half8 __attribute__((ext_vector_type(8)));
typedef float f32x4 __attribute__((ext_vector_type(4)));

// MFMA transform + fused histogram (dst>>5).
// Transform: block = 4 waves x 16 nodes = 64 nodes; 16 x mfma_f32_16x16x32_f16.
// A[row=l&15][k=32*kk+8*(l>>4)+j], B[k same][col=l&15] (consistent kappa
// cancels); C/D (HW-verified): col=lane&15, row=(lane>>4)*4+reg.
// pk chunk layout (consumer lane16 = chunk c): t=c&1 (0=mean,1=var), o=c>>1;
// uint j of chunk holds features 8o+2j, 8o+2j+1.
__global__ __launch_bounds__(256) void k_transform_hist(const float* __restrict__ mean,
                                                        const float* __restrict__ stdv,
                                                        const float* __restrict__ Wm,
                                                        const float* __restrict__ Ws,
                                                        uint* __restrict__ pk, int n,
                                                        const int* __restrict__ ei, int E,
                                                        int* __restrict__ bcnt) {
    __shared__ float sW[2 * 4096];
    __shared__ int lh[NB3];
    for (int i = threadIdx.x; i < 4096; i += 256) {
        sW[i] = Wm[i];
        sW[4096 + i] = Ws[i];
    }
    for (int i = threadIdx.x; i < NB3; i += 256) lh[i] = 0;
    __syncthreads();

    for (int t = blockIdx.x * 256 + threadIdx.x; t < E; t += gridDim.x * 256)
        atomicAdd(&lh[ei[E + t] >> 5], 1);
    __syncthreads();
    for (int i = threadIdx.x; i < NB3; i += 256)
        if (lh[i]) atomicAdd(&bcnt[i], lh[i]);

    const int lane = threadIdx.x & 63;
    const int wid  = threadIdx.x >> 6;
    const int l16  = lane & 15;
    const int lg   = lane >> 4;          // 0..3

    half8 bw[2][2][4];
#pragma unroll
    for (int t = 0; t < 2; ++t)
#pragma unroll
        for (int kk = 0; kk < 2; ++kk)
#pragma unroll
            for (int c = 0; c < 4; ++c) {
                half8 h;
#pragma unroll
                for (int j = 0; j < 8; ++j)
                    h[j] = (_Float16)sW[t * 4096 + (32 * kk + 8 * lg + j) * 64 + 16 * c + l16];
                bw[t][kk][c] = h;
            }

    const int nb = blockIdx.x * 64 + wid * 16;
    int arow = nb + l16;
    if (arow >= n) arow = n - 1;         // clamp; rows >= n never stored

    half8 am[2], av[2];
#pragma unroll
    for (int kk = 0; kk < 2; ++kk) {
        const float* mp = mean + (size_t)arow * 64 + 32 * kk + 8 * lg;
        const float* sp = stdv + (size_t)arow * 64 + 32 * kk + 8 * lg;
        float4 m0 = *(const float4*)mp;
        float4 m1 = *(const float4*)(mp + 4);
        float4 s0 = *(const float4*)sp;
        float4 s1 = *(const float4*)(sp + 4);
        half8 a, v;
        a[0] = (_Float16)m0.x; a[1] = (_Float16)m0.y;
        a[2] = (_Float16)m0.z; a[3] = (_Float16)m0.w;
        a[4] = (_Float16)m1.x; a[5] = (_Float16)m1.y;
        a[6] = (_Float16)m1.z; a[7] = (_Float16)m1.w;
        v[0] = (_Float16)(s0.x * s0.x); v[1] = (_Float16)(s0.y * s0.y);
        v[2] = (_Float16)(s0.z * s0.z); v[3] = (_Float16)(s0.w * s0.w);
        v[4] = (_Float16)(s1.x * s1.x); v[5] = (_Float16)(s1.y * s1.y);
        v[6] = (_Float16)(s1.z * s1.z); v[7] = (_Float16)(s1.w * s1.w);
        am[kk] = a; av[kk] = v;
    }

    f32x4 accm[4], accs[4];
    const f32x4 z = {0.f, 0.f, 0.f, 0.f};
#pragma unroll
    for (int c = 0; c < 4; ++c) { accm[c] = z; accs[c] = z; }

#pragma unroll
    for (int c = 0; c < 4; ++c) {
        accm[c] = __builtin_amdgcn_mfma_f32_16x16x32_f16(am[0], bw[0][0][c], accm[c], 0, 0, 0);
        accm[c] = __builtin_amdgcn_mfma_f32_16x16x32_f16(am[1], bw[0][1][c], accm[c], 0, 0, 0);
        accs[c] = __builtin_amdgcn_mfma_f32_16x16x32_f16(av[0], bw[1][0][c], accs[c], 0, 0, 0);
        accs[c] = __builtin_amdgcn_mfma_f32_16x16x32_f16(av[1], bw[1][1][c], accs[c], 0, 0, 0);
    }

#pragma unroll
    for (int c = 0; c < 4; ++c) {
        const int F = 16 * c + l16;
#pragma unroll
        for (int r = 0; r < 4; ++r) {
            int node = nb + 4 * lg + r;
            float mv = accm[c][r];
            float vv = accs[c][r];
            float mp = __shfl_xor(mv, 1, 64);
            float vp = __shfl_xor(vv, 1, 64);
            if (!(l16 & 1) && node < n) {
                int o = F >> 3, j = (F & 7) >> 1;
                __half2 hm = __floats2half2_rn(mv, mp);
                __half2 hv = __floats2half2_rn(vv, vp);
                pk[(size_t)node * 64 + 8 * o + j]     = *reinterpret_cast<uint*>(&hm);
                pk[(size_t)node * 64 + 8 * o + 4 + j] = *reinterpret_cast<uint*>(&hv);
            }
        }
    }
}

// block 0: exclusive scan of bcnt[NB3] (two 1024-wide rounds) -> sbase, bcur;
// block 1: KL reduction.
__global__ __launch_bounds__(1024) void k_scan_kl(const int* __restrict__ bcnt,
                                                  int* __restrict__ sbase,
                                                  int* __restrict__ bcur,
                                                  const float* __restrict__ Wm_mu,
                                                  const float* __restrict__ Wm_ls,
                                                  const float* __restrict__ Ws_mu,
                                                  const float* __restrict__ Ws_ls,
                                                  float* __restrict__ okl) {
    if (blockIdx.x == 0) {
        __shared__ int s[1024];
        __shared__ int carry;
        // round 0: indices 0..1023
        int v = bcnt[threadIdx.x];
        s[threadIdx.x] = v;
        __syncthreads();
        for (int off = 1; off < 1024; off <<= 1) {
            int t = 0;
            if (threadIdx.x >= off) t = s[threadIdx.x - off];
            __syncthreads();
            s[threadIdx.x] += t;
            __syncthreads();
        }
        int excl = s[threadIdx.x] - v;
        sbase[threadIdx.x] = excl;
        bcur[threadIdx.x] = excl;
        if (threadIdx.x == 1023) carry = s[1023];
        __syncthreads();
        // round 1: indices 1024..2047 (valid through NB3)
        int i = 1024 + threadIdx.x;
        int v2 = (i < NB3) ? bcnt[i] : 0;
        s[threadIdx.x] = v2;
        __syncthreads();
        for (int off = 1; off < 1024; off <<= 1) {
            int t = 0;
            if (threadIdx.x >= off) t = s[threadIdx.x - off];
            __syncthreads();
            s[threadIdx.x] += t;
            __syncthreads();
        }
        int excl2 = s[threadIdx.x] - v2 + carry;
        if (i <= NB3) {                      // sbase[NB3] = E
            sbase[i] = excl2;
            bcur[i] = excl2;
        }
    } else {
        __shared__ float red[1024];
        const float C = -2.3025850929940457f - 0.5f;   // log(0.1) - 0.5
        float acc = 0.f;
        for (int i = threadIdx.x; i < 4096; i += 1024) {
            {
                float mu = Wm_mu[i], ls = Wm_ls[i];
                float s = expf(ls);
                acc += C - ls + (s * s + mu * mu) * 50.0f;  // 1/(2*0.1^2)
            }
            {
                float mu = Ws_mu[i], ls = Ws_ls[i];
                float s = expf(ls);
                acc += C - ls + (s * s + mu * mu) * 50.0f;
            }
        }
        red[threadIdx.x] = acc;
        __syncthreads();
        for (int s = 512; s > 0; s >>= 1) {
            if (threadIdx.x < s) red[threadIdx.x] += red[threadIdx.x + s];
            __syncthreads();
        }
        if (threadIdx.x == 0) okl[0] = red[0];
    }
}

// Two-pass grouping by bucket (dst>>5). SBLK edges per block, 512 threads.
// Pass A: count into lcnt; reserve one global cursor range per bucket;
// pass B: re-read (L2-hot), rank via lcnt2, write ~10-edge contiguous runs.
__global__ __launch_bounds__(512) void k_bucket_scatter(const int* __restrict__ ei,
                                                        const float* __restrict__ ew,
                                                        int* __restrict__ bcur,
                                                        uint* __restrict__ esrcw,
                                                        uchar* __restrict__ dlo, int E) {
    __shared__ int lcnt[NB3], lpos[NB3], lcnt2[NB3];
    for (int i = threadIdx.x; i < NB3; i += 512) {
        lcnt[i] = 0;
        lcnt2[i] = 0;
    }
    __syncthreads();
    const int base = blockIdx.x * SBLK;
#pragma unroll
    for (int u = 0; u < SBLK / 512; ++u) {
        int gi = base + u * 512 + threadIdx.x;
        if (gi < E) atomicAdd(&lcnt[ei[E + gi] >> 5], 1);
    }
    __syncthreads();
    for (int i = threadIdx.x; i < NB3; i += 512)
        lpos[i] = lcnt[i] ? atomicAdd(&bcur[i], lcnt[i]) : 0;
    __syncthreads();
#pragma unroll
    for (int u = 0; u < SBLK / 512; ++u) {
        int gi = base + u * 512 + threadIdx.x;
        if (gi < E) {
            int d = ei[E + gi];
            int bkt = d >> 5;
            uint w16 = (uint)__half_as_ushort(__float2half(ew[gi]));
            int pos = lpos[bkt] + atomicAdd(&lcnt2[bkt], 1);
            esrcw[pos] = (w16 << 16) | (uint)ei[gi];
            dlo[pos] = (uchar)(d & 31);
        }
    }
}

// Fused local sort + aggregate. Block = one bucket (32 nodes, ~1024 records).
// 256 threads = 4 waves; ~6.7 KB LDS -> 8 blocks/CU, all 1564 blocks resident.
__global__ __launch_bounds__(256) void k_sub_agg(const int* __restrict__ sbase,
                                                 const uint* __restrict__ esrcw,
                                                 const uchar* __restrict__ dlo,
                                                 const uint* __restrict__ pk,
                                                 const float* __restrict__ bm,
                                                 const float* __restrict__ bs,
                                                 float* __restrict__ om,
                                                 float* __restrict__ os, int nv) {
    __shared__ int ncnt[32], sc[32], noff[33], cur[32];
    __shared__ uint sorted[SCAP];
    const int tid  = threadIdx.x;
    const int b    = blockIdx.x;
    const int base = sbase[b];
    int cnt = sbase[b + 1] - base;
    if (cnt > SCAP) cnt = SCAP;          // statistically impossible (~16 sigma)

    if (tid < 32) ncnt[tid] = 0;
    __syncthreads();
    for (int i = tid; i < cnt; i += 256)
        atomicAdd(&ncnt[dlo[base + i]], 1);
    __syncthreads();
    if (tid < 32) sc[tid] = ncnt[tid];
    __syncthreads();
    for (int off = 1; off < 32; off <<= 1) {
        int t = 0;
        if (tid < 32 && tid >= off) t = sc[tid - off];
        __syncthreads();
        if (tid < 32) sc[tid] += t;
        __syncthreads();
    }
    if (tid < 32) {
        int excl = sc[tid] - ncnt[tid];
        noff[tid] = excl;
        cur[tid] = excl;
        if (tid == 31) noff[32] = sc[31];
    }
    __syncthreads();
    for (int i = tid; i < cnt; i += 256) {
        int d = dlo[base + i];
        int pos = atomicAdd(&cur[d], 1);
        sorted[pos] = esrcw[base + i];
    }
    __syncthreads();

    const int lane = tid & 63;
    const int wave = tid >> 6;       // 0..3
    const int g    = lane >> 4;      // edge subgroup 0..3
    const int l16  = lane & 15;      // chunk id: t=l16&1, o=l16>>1
    const int t    = l16 & 1;

    for (int ln = wave * 8; ln < wave * 8 + 8; ++ln) {
        const int node = b * 32 + ln;
        const int st = noff[ln];
        const int cn = noff[ln + 1] - st;

        float accf[8] = {0.f, 0.f, 0.f, 0.f, 0.f, 0.f, 0.f, 0.f};

        for (int be = 0; be < cn; be += 64) {
            int m = cn - be;
            if (m > 64) m = 64;
            uint rec = 0;                          // w16=0 -> w=0.0f
            if (lane < m) rec = sorted[st + be + lane];
            int mr = (m + 31) & ~31;               // 32 or 64

            for (int j0 = 0; j0 < mr; j0 += 32) {
                uint rr[8];
#pragma unroll
                for (int u = 0; u < 8; ++u)
                    rr[u] = (uint)__shfl((int)rec, j0 + 4 * u + g, 64);
                uint4 dd[8];
#pragma unroll
                for (int u = 0; u < 8; ++u)
                    dd[u] = *reinterpret_cast<const uint4*>(
                        pk + (size_t)(rr[u] & 0xFFFFu) * 64 + l16 * 4);
                __half2 wh[8];
#pragma unroll
                for (int u = 0; u < 8; ++u) {
                    float w = __half2float(__ushort_as_half((ushort)(rr[u] >> 16)));
                    float wl = t ? w * w : w;
                    __half h = __float2half(wl);
                    wh[u] = __halves2half2(h, h);
                }
                __half2 a0 = __halves2half2(__half(0.f), __half(0.f));
                __half2 a1 = a0, a2 = a0, a3 = a0;
#pragma unroll
                for (int u = 0; u < 8; ++u) {
                    a0 = __hfma2(*reinterpret_cast<__half2*>(&dd[u].x), wh[u], a0);
                    a1 = __hfma2(*reinterpret_cast<__half2*>(&dd[u].y), wh[u], a1);
                    a2 = __hfma2(*reinterpret_cast<__half2*>(&dd[u].z), wh[u], a2);
                    a3 = __hfma2(*reinterpret_cast<__half2*>(&dd[u].w), wh[u], a3);
                }
                float2 f;
                f = __half22float2(a0); accf[0] += f.x; accf[1] += f.y;
                f = __half22float2(a1); accf[2] += f.x; accf[3] += f.y;
                f = __half22float2(a2); accf[4] += f.x; accf[5] += f.y;
                f = __half22float2(a3); accf[6] += f.x; accf[7] += f.y;
            }
        }

#pragma unroll
        for (int c = 0; c < 8; ++c) {
            accf[c] += __shfl_xor(accf[c], 16, 64);
            accf[c] += __shfl_xor(accf[c], 32, 64);
        }
        // Lane l16 holds accf[c] = aggregated feature 8*(l16>>1)+c of type l16&1.

        if (g == 0 && node < nv) {
            const int f0 = (l16 >> 1) * 8;
            if (!t) {
                float4 b0 = *reinterpret_cast<const float4*>(bm + f0);
                float4 b1 = *reinterpret_cast<const float4*>(bm + f0 + 4);
                float4 r0 = {accf[0] + b0.x, accf[1] + b0.y, accf[2] + b0.z, accf[3] + b0.w};
                float4 r1 = {accf[4] + b1.x, accf[5] + b1.y, accf[6] + b1.z, accf[7] + b1.w};
                *reinterpret_cast<float4*>(om + (size_t)node * 64 + f0)     = r0;
                *reinterpret_cast<float4*>(om + (size_t)node * 64 + f0 + 4) = r1;
            } else {
                float4 b0 = *reinterpret_cast<const float4*>(bs + f0);
                float4 b1 = *reinterpret_cast<const float4*>(bs + f0 + 4);
                float4 r0, r1;
                r0.x = sqrtf(expf(accf[0] + b0.x) + 1e-6f);
                r0.y = sqrtf(expf(accf[1] + b0.y) + 1e-6f);
                r0.z = sqrtf(expf(accf[2] + b0.z) + 1e-6f);
                r0.w = sqrtf(expf(accf[3] + b0.w) + 1e-6f);
                r1.x = sqrtf(expf(accf[4] + b1.x) + 1e-6f);
                r1.y = sqrtf(expf(accf[5] + b1.y) + 1e-6f);
                r1.z = sqrtf(expf(accf[6] + b1.z) + 1e-6f);
                r1.w = sqrtf(expf(accf[7] + b1.w) + 1e-6f);
                *reinterpret_cast<float4*>(os + (size_t)node * 64 + f0)     = r0;
                *reinterpret_cast<float4*>(os + (size_t)node * 64 + f0 + 4) = r1;
            }
        }
    }
}

extern "C" void kernel_launch(void* const* d_in, const int* in_sizes, int n_in,
                              void* d_out, int out_size, void* d_ws, size_t ws_size,
                              hipStream_t stream) {
    const float* mean  = (const float*)d_in[0];
    const float* stdv  = (const float*)d_in[1];
    const int*   ei    = (const int*)d_in[2];
    const float* ew    = (const float*)d_in[3];
    const float* Wm_mu = (const float*)d_in[4];
    const float* Wm_ls = (const float*)d_in[5];
    const float* bm    = (const float*)d_in[6];
    const float* Ws_mu = (const float*)d_in[7];
    const float* Ws_ls = (const float*)d_in[8];
    const float* bs    = (const float*)d_in[9];

    const int n = in_sizes[0] / 64;   // 50000
    const int E = in_sizes[3];        // 1600000
    const int total = n * 64;

    float* om  = (float*)d_out;
    float* os  = om + total;
    float* okl = om + 2 * total;

    char* wsb = (char*)d_ws;
    int* bcnt    = (int*)wsb;                     // 2048
    int* sbase   = bcnt + 2048;                   // 2080
    int* bcur    = sbase + 2080;                  // 2048
    uchar* dlo   = (uchar*)(bcur + 2048);         // E bytes
    size_t es_off = ((size_t)((char*)(dlo + E) - wsb) + 15) & ~(size_t)15;
    uint* esrcw  = (uint*)(wsb + es_off);         // E
    size_t pk_off = ((size_t)((char*)(esrcw + E) - wsb) + 15) & ~(size_t)15;
    uint* pk     = (uint*)(wsb + pk_off);         // total (~21 MB overall)

    hipMemsetAsync(bcnt, 0, 2048 * sizeof(int), stream);
    k_transform_hist<<<(n + 63) / 64, 256, 0, stream>>>(mean, stdv, Wm_mu, Ws_mu,
                                                        pk, n, ei, E, bcnt);
    k_scan_kl<<<2, 1024, 0, stream>>>(bcnt, sbase, bcur,
                                      Wm_mu, Wm_ls, Ws_mu, Ws_ls, okl);
    k_bucket_scatter<<<(E + SBLK - 1) / SBLK, 512, 0, stream>>>(ei, ew, bcur,
                                                                esrcw, dlo, E);
    k_sub_agg<<<NB3, 256, 0, stream>>>(sbase, esrcw, dlo, pk, bm, bs, om, os, n);
}

// Round 13
// 149.309 us; speedup vs baseline: 1.0139x; 1.0139x over previous
//
#include <hip/hip_runtime.h>
#include <hip/hip_fp16.h>
#include <math.h>

// H = 64, N = 50000 nodes, E = 1.6M edges.
// d_out = [ new_mean (N*64) | new_std (N*64) | total_kl (1) ]
//
// Pipeline:
//   1. k_transform_hist: MFMA h_m = mean@Wm, h_v = (std^2)@Ws -> pk (fp16
//      chunk layout, 256 B/node) + fused grid-stride 1564-bucket histogram
//      of dst>>5.
//   2. k_scan_kl: block 0 = two-round 1024-wide exclusive scan of bucket
//      counts (-> sbase, bcur); block 1 = KL reduction.
//   3. k_bucket_scatter: SINGLE-pass, 4096 edges per 256-thr block (391
//      blocks), register ranks, 1 LDS atomic/edge, one global cursor atomic
//      per (block, bucket).
//   4. k_sub_agg: one block per bucket (32 nodes, ~1024 records, 256 thr,
//      4 waves, ~6.7 KB LDS -> 8 blocks/CU, ALL blocks resident); counting
//      sort into LDS, wave-per-node register reduce, fused epilogue.
//
// Lesson log: r10 LDS-atomic accumulation = 17x regression; r5 forced
// occupancy = spills; r11 782-block agg left a grid tail; r12 two-pass
// 98-block scatter = 3x regression (grid width beats write coalescing).
//
// ws: bcnt[2048] | sbase[2080] | bcur[2048] | dlo uchar[E] | esrcw uint[E]
//     | pk uint[n*64]   (~21 MB)

#define NB3  1564                // buckets (dst >> 5), 32 nodes each
#define SCAP 1536                // max records/bucket (mean 1024, ~16 sigma)

typedef _Float16 half8 __attribute__((ext_vector_type(8)));
typedef float f32x4 __attribute__((ext_vector_type(4)));

// MFMA transform + fused histogram (dst>>5).
// Transform: block = 4 waves x 16 nodes = 64 nodes; 16 x mfma_f32_16x16x32_f16.
// A[row=l&15][k=32*kk+8*(l>>4)+j], B[k same][col=l&15] (consistent kappa
// cancels); C/D (HW-verified): col=lane&15, row=(lane>>4)*4+reg.
// pk chunk layout (consumer lane16 = chunk c): t=c&1 (0=mean,1=var), o=c>>1;
// uint j of chunk holds features 8o+2j, 8o+2j+1.
__global__ __launch_bounds__(256) void k_transform_hist(const float* __restrict__ mean,
                                                        const float* __restrict__ stdv,
                                                        const float* __restrict__ Wm,
                                                        const float* __restrict__ Ws,
                                                        uint* __restrict__ pk, int n,
                                                        const int* __restrict__ ei, int E,
                                                        int* __restrict__ bcnt) {
    __shared__ float sW[2 * 4096];
    __shared__ int lh[NB3];
    for (int i = threadIdx.x; i < 4096; i += 256) {
        sW[i] = Wm[i];
        sW[4096 + i] = Ws[i];
    }
    for (int i = threadIdx.x; i < NB3; i += 256) lh[i] = 0;
    __syncthreads();

    for (int t = blockIdx.x * 256 + threadIdx.x; t < E; t += gridDim.x * 256)
        atomicAdd(&lh[ei[E + t] >> 5], 1);
    __syncthreads();
    for (int i = threadIdx.x; i < NB3; i += 256)
        if (lh[i]) atomicAdd(&bcnt[i], lh[i]);

    const int lane = threadIdx.x & 63;
    const int wid  = threadIdx.x >> 6;
    const int l16  = lane & 15;
    const int lg   = lane >> 4;          // 0..3

    half8 bw[2][2][4];
#pragma unroll
    for (int t = 0; t < 2; ++t)
#pragma unroll
        for (int kk = 0; kk < 2; ++kk)
#pragma unroll
            for (int c = 0; c < 4; ++c) {
                half8 h;
#pragma unroll
                for (int j = 0; j < 8; ++j)
                    h[j] = (_Float16)sW[t * 4096 + (32 * kk + 8 * lg + j) * 64 + 16 * c + l16];
                bw[t][kk][c] = h;
            }

    const int nb = blockIdx.x * 64 + wid * 16;
    int arow = nb + l16;
    if (arow >= n) arow = n - 1;         // clamp; rows >= n never stored

    half8 am[2], av[2];
#pragma unroll
    for (int kk = 0; kk < 2; ++kk) {
        const float* mp = mean + (size_t)arow * 64 + 32 * kk + 8 * lg;
        const float* sp = stdv + (size_t)arow * 64 + 32 * kk + 8 * lg;
        float4 m0 = *(const float4*)mp;
        float4 m1 = *(const float4*)(mp + 4);
        float4 s0 = *(const float4*)sp;
        float4 s1 = *(const float4*)(sp + 4);
        half8 a, v;
        a[0] = (_Float16)m0.x; a[1] = (_Float16)m0.y;
        a[2] = (_Float16)m0.z; a[3] = (_Float16)m0.w;
        a[4] = (_Float16)m1.x; a[5] = (_Float16)m1.y;
        a[6] = (_Float16)m1.z; a[7] = (_Float16)m1.w;
        v[0] = (_Float16)(s0.x * s0.x); v[1] = (_Float16)(s0.y * s0.y);
        v[2] = (_Float16)(s0.z * s0.z); v[3] = (_Float16)(s0.w * s0.w);
        v[4] = (_Float16)(s1.x * s1.x); v[5] = (_Float16)(s1.y * s1.y);
        v[6] = (_Float16)(s1.z * s1.z); v[7] = (_Float16)(s1.w * s1.w);
        am[kk] = a; av[kk] = v;
    }

    f32x4 accm[4], accs[4];
    const f32x4 z = {0.f, 0.f, 0.f, 0.f};
#pragma unroll
    for (int c = 0; c < 4; ++c) { accm[c] = z; accs[c] = z; }

#pragma unroll
    for (int c = 0; c < 4; ++c) {
        accm[c] = __builtin_amdgcn_mfma_f32_16x16x32_f16(am[0], bw[0][0][c], accm[c], 0, 0, 0);
        accm[c] = __builtin_amdgcn_mfma_f32_16x16x32_f16(am[1], bw[0][1][c], accm[c], 0, 0, 0);
        accs[c] = __builtin_amdgcn_mfma_f32_16x16x32_f16(av[0], bw[1][0][c], accs[c], 0, 0, 0);
        accs[c] = __builtin_amdgcn_mfma_f32_16x16x32_f16(av[1], bw[1][1][c], accs[c], 0, 0, 0);
    }

#pragma unroll
    for (int c = 0; c < 4; ++c) {
        const int F = 16 * c + l16;
#pragma unroll
        for (int r = 0; r < 4; ++r) {
            int node = nb + 4 * lg + r;
            float mv = accm[c][r];
            float vv = accs[c][r];
            float mp = __shfl_xor(mv, 1, 64);
            float vp = __shfl_xor(vv, 1, 64);
            if (!(l16 & 1) && node < n) {
                int o = F >> 3, j = (F & 7) >> 1;
                __half2 hm = __floats2half2_rn(mv, mp);
                __half2 hv = __floats2half2_rn(vv, vp);
                pk[(size_t)node * 64 + 8 * o + j]     = *reinterpret_cast<uint*>(&hm);
                pk[(size_t)node * 64 + 8 * o + 4 + j] = *reinterpret_cast<uint*>(&hv);
            }
        }
    }
}

// block 0: exclusive scan of bcnt[NB3] (two 1024-wide rounds) -> sbase, bcur;
// block 1: KL reduction.
__global__ __launch_bounds__(1024) void k_scan_kl(const int* __restrict__ bcnt,
                                                  int* __restrict__ sbase,
                                                  int* __restrict__ bcur,
                                                  const float* __restrict__ Wm_mu,
                                                  const float* __restrict__ Wm_ls,
                                                  const float* __restrict__ Ws_mu,
                                                  const float* __restrict__ Ws_ls,
                                                  float* __restrict__ okl) {
    if (blockIdx.x == 0) {
        __shared__ int s[1024];
        __shared__ int carry;
        int v = bcnt[threadIdx.x];
        s[threadIdx.x] = v;
        __syncthreads();
        for (int off = 1; off < 1024; off <<= 1) {
            int t = 0;
            if (threadIdx.x >= off) t = s[threadIdx.x - off];
            __syncthreads();
            s[threadIdx.x] += t;
            __syncthreads();
        }
        int excl = s[threadIdx.x] - v;
        sbase[threadIdx.x] = excl;
        bcur[threadIdx.x] = excl;
        if (threadIdx.x == 1023) carry = s[1023];
        __syncthreads();
        int i = 1024 + threadIdx.x;
        int v2 = (i < NB3) ? bcnt[i] : 0;
        s[threadIdx.x] = v2;
        __syncthreads();
        for (int off = 1; off < 1024; off <<= 1) {
            int t = 0;
            if (threadIdx.x >= off) t = s[threadIdx.x - off];
            __syncthreads();
            s[threadIdx.x] += t;
            __syncthreads();
        }
        int excl2 = s[threadIdx.x] - v2 + carry;
        if (i <= NB3) {                      // sbase[NB3] = E
            sbase[i] = excl2;
            bcur[i] = excl2;
        }
    } else {
        __shared__ float red[1024];
        const float C = -2.3025850929940457f - 0.5f;   // log(0.1) - 0.5
        float acc = 0.f;
        for (int i = threadIdx.x; i < 4096; i += 1024) {
            {
                float mu = Wm_mu[i], ls = Wm_ls[i];
                float s = expf(ls);
                acc += C - ls + (s * s + mu * mu) * 50.0f;  // 1/(2*0.1^2)
            }
            {
                float mu = Ws_mu[i], ls = Ws_ls[i];
                float s = expf(ls);
                acc += C - ls + (s * s + mu * mu) * 50.0f;
            }
        }
        red[threadIdx.x] = acc;
        __syncthreads();
        for (int s = 512; s > 0; s >>= 1) {
            if (threadIdx.x < s) red[threadIdx.x] += red[threadIdx.x + s];
            __syncthreads();
        }
        if (threadIdx.x == 0) okl[0] = red[0];
    }
}

// Single-pass grouping by bucket (dst>>5). 4096 edges per 256-thread block
// (391 blocks); register ranks rr[16]; 1 LDS atomic per edge; one global
// cursor atomic per (block, non-empty bucket).
__global__ __launch_bounds__(256) void k_bucket_scatter(const int* __restrict__ ei,
                                                        const float* __restrict__ ew,
                                                        int* __restrict__ bcur,
                                                        uint* __restrict__ esrcw,
                                                        uchar* __restrict__ dlo, int E) {
    __shared__ int lcnt[NB3], lpos[NB3];
    for (int i = threadIdx.x; i < NB3; i += 256) lcnt[i] = 0;
    __syncthreads();
    const int base = blockIdx.x * 4096;
    int rr[16];
#pragma unroll
    for (int u = 0; u < 16; ++u) {
        int gi = base + u * 256 + threadIdx.x;
        if (gi < E) rr[u] = atomicAdd(&lcnt[ei[E + gi] >> 5], 1);
    }
    __syncthreads();
    for (int i = threadIdx.x; i < NB3; i += 256)
        lpos[i] = lcnt[i] ? atomicAdd(&bcur[i], lcnt[i]) : 0;
    __syncthreads();
#pragma unroll
    for (int u = 0; u < 16; ++u) {
        int gi = base + u * 256 + threadIdx.x;
        if (gi < E) {
            int d = ei[E + gi];
            uint w16 = (uint)__half_as_ushort(__float2half(ew[gi]));
            int pos = lpos[d >> 5] + rr[u];
            esrcw[pos] = (w16 << 16) | (uint)ei[gi];
            dlo[pos] = (uchar)(d & 31);
        }
    }
}

// Fused local sort + aggregate. Block = one bucket (32 nodes, ~1024 records).
// 256 threads = 4 waves; ~6.7 KB LDS -> 8 blocks/CU, all 1564 blocks resident.
__global__ __launch_bounds__(256) void k_sub_agg(const int* __restrict__ sbase,
                                                 const uint* __restrict__ esrcw,
                                                 const uchar* __restrict__ dlo,
                                                 const uint* __restrict__ pk,
                                                 const float* __restrict__ bm,
                                                 const float* __restrict__ bs,
                                                 float* __restrict__ om,
                                                 float* __restrict__ os, int nv) {
    __shared__ int ncnt[32], sc[32], noff[33], cur[32];
    __shared__ uint sorted[SCAP];
    const int tid  = threadIdx.x;
    const int b    = blockIdx.x;
    const int base = sbase[b];
    int cnt = sbase[b + 1] - base;
    if (cnt > SCAP) cnt = SCAP;          // statistically impossible (~16 sigma)

    if (tid < 32) ncnt[tid] = 0;
    __syncthreads();
    for (int i = tid; i < cnt; i += 256)
        atomicAdd(&ncnt[dlo[base + i]], 1);
    __syncthreads();
    if (tid < 32) sc[tid] = ncnt[tid];
    __syncthreads();
    for (int off = 1; off < 32; off <<= 1) {
        int t = 0;
        if (tid < 32 && tid >= off) t = sc[tid - off];
        __syncthreads();
        if (tid < 32) sc[tid] += t;
        __syncthreads();
    }
    if (tid < 32) {
        int excl = sc[tid] - ncnt[tid];
        noff[tid] = excl;
        cur[tid] = excl;
        if (tid == 31) noff[32] = sc[31];
    }
    __syncthreads();
    for (int i = tid; i < cnt; i += 256) {
        int d = dlo[base + i];
        int pos = atomicAdd(&cur[d], 1);
        sorted[pos] = esrcw[base + i];
    }
    __syncthreads();

    const int lane = tid & 63;
    const int wave = tid >> 6;       // 0..3
    const int g    = lane >> 4;      // edge subgroup 0..3
    const int l16  = lane & 15;      // chunk id: t=l16&1, o=l16>>1
    const int t    = l16 & 1;

    for (int ln = wave * 8; ln < wave * 8 + 8; ++ln) {
        const int node = b * 32 + ln;
        const int st = noff[ln];
        const int cn = noff[ln + 1] - st;

        float accf[8] = {0.f, 0.f, 0.f, 0.f, 0.f, 0.f, 0.f, 0.f};

        for (int be = 0; be < cn; be += 64) {
            int m = cn - be;
            if (m > 64) m = 64;
            uint rec = 0;                          // w16=0 -> w=0.0f
            if (lane < m) rec = sorted[st + be + lane];
            int mr = (m + 31) & ~31;               // 32 or 64

            for (int j0 = 0; j0 < mr; j0 += 32) {
                uint rr[8];
#pragma unroll
                for (int u = 0; u < 8; ++u)
                    rr[u] = (uint)__shfl((int)rec, j0 + 4 * u + g, 64);
                uint4 dd[8];
#pragma unroll
                for (int u = 0; u < 8; ++u)
                    dd[u] = *reinterpret_cast<const uint4*>(
                        pk + (size_t)(rr[u] & 0xFFFFu) * 64 + l16 * 4);
                __half2 wh[8];
#pragma unroll
                for (int u = 0; u < 8; ++u) {
                    float w = __half2float(__ushort_as_half((ushort)(rr[u] >> 16)));
                    float wl = t ? w * w : w;
                    __half h = __float2half(wl);
                    wh[u] = __halves2half2(h, h);
                }
                __half2 a0 = __halves2half2(__half(0.f), __half(0.f));
                __half2 a1 = a0, a2 = a0, a3 = a0;
#pragma unroll
                for (int u = 0; u < 8; ++u) {
                    a0 = __hfma2(*reinterpret_cast<__half2*>(&dd[u].x), wh[u], a0);
                    a1 = __hfma2(*reinterpret_cast<__half2*>(&dd[u].y), wh[u], a1);
                    a2 = __hfma2(*reinterpret_cast<__half2*>(&dd[u].z), wh[u], a2);
                    a3 = __hfma2(*reinterpret_cast<__half2*>(&dd[u].w), wh[u], a3);
                }
                float2 f;
                f = __half22float2(a0); accf[0] += f.x; accf[1] += f.y;
                f = __half22float2(a1); accf[2] += f.x; accf[3] += f.y;
                f = __half22float2(a2); accf[4] += f.x; accf[5] += f.y;
                f = __half22float2(a3); accf[6] += f.x; accf[7] += f.y;
            }
        }

#pragma unroll
        for (int c = 0; c < 8; ++c) {
            accf[c] += __shfl_xor(accf[c], 16, 64);
            accf[c] += __shfl_xor(accf[c], 32, 64);
        }
        // Lane l16 holds accf[c] = aggregated feature 8*(l16>>1)+c of type l16&1.

        if (g == 0 && node < nv) {
            const int f0 = (l16 >> 1) * 8;
            if (!t) {
                float4 b0 = *reinterpret_cast<const float4*>(bm + f0);
                float4 b1 = *reinterpret_cast<const float4*>(bm + f0 + 4);
                float4 r0 = {accf[0] + b0.x, accf[1] + b0.y, accf[2] + b0.z, accf[3] + b0.w};
                float4 r1 = {accf[4] + b1.x, accf[5] + b1.y, accf[6] + b1.z, accf[7] + b1.w};
                *reinterpret_cast<float4*>(om + (size_t)node * 64 + f0)     = r0;
                *reinterpret_cast<float4*>(om + (size_t)node * 64 + f0 + 4) = r1;
            } else {
                float4 b0 = *reinterpret_cast<const float4*>(bs + f0);
                float4 b1 = *reinterpret_cast<const float4*>(bs + f0 + 4);
                float4 r0, r1;
                r0.x = sqrtf(expf(accf[0] + b0.x) + 1e-6f);
                r0.y = sqrtf(expf(accf[1] + b0.y) + 1e-6f);
                r0.z = sqrtf(expf(accf[2] + b0.z) + 1e-6f);
                r0.w = sqrtf(expf(accf[3] + b0.w) + 1e-6f);
                r1.x = sqrtf(expf(accf[4] + b1.x) + 1e-6f);
                r1.y = sqrtf(expf(accf[5] + b1.y) + 1e-6f);
                r1.z = sqrtf(expf(accf[6] + b1.z) + 1e-6f);
                r1.w = sqrtf(expf(accf[7] + b1.w) + 1e-6f);
                *reinterpret_cast<float4*>(os + (size_t)node * 64 + f0)     = r0;
                *reinterpret_cast<float4*>(os + (size_t)node * 64 + f0 + 4) = r1;
            }
        }
    }
}

extern "C" void kernel_launch(void* const* d_in, const int* in_sizes, int n_in,
                              void* d_out, int out_size, void* d_ws, size_t ws_size,
                              hipStream_t stream) {
    const float* mean  = (const float*)d_in[0];
    const float* stdv  = (const float*)d_in[1];
    const int*   ei    = (const int*)d_in[2];
    const float* ew    = (const float*)d_in[3];
    const float* Wm_mu = (const float*)d_in[4];
    const float* Wm_ls = (const float*)d_in[5];
    const float* bm    = (const float*)d_in[6];
    const float* Ws_mu = (const float*)d_in[7];
    const float* Ws_ls = (const float*)d_in[8];
    const float* bs    = (const float*)d_in[9];

    const int n = in_sizes[0] / 64;   // 50000
    const int E = in_sizes[3];        // 1600000
    const int total = n * 64;

    float* om  = (float*)d_out;
    float* os  = om + total;
    float* okl = om + 2 * total;

    char* wsb = (char*)d_ws;
    int* bcnt    = (int*)wsb;                     // 2048
    int* sbase   = bcnt + 2048;                   // 2080
    int* bcur    = sbase + 2080;                  // 2048
    uchar* dlo   = (uchar*)(bcur + 2048);         // E bytes
    size_t es_off = ((size_t)((char*)(dlo + E) - wsb) + 15) & ~(size_t)15;
    uint* esrcw  = (uint*)(wsb + es_off);         // E
    size_t pk_off = ((size_t)((char*)(esrcw + E) - wsb) + 15) & ~(size_t)15;
    uint* pk     = (uint*)(wsb + pk_off);         // total (~21 MB overall)

    hipMemsetAsync(bcnt, 0, 2048 * sizeof(int), stream);
    k_transform_hist<<<(n + 63) / 64, 256, 0, stream>>>(mean, stdv, Wm_mu, Ws_mu,
                                                        pk, n, ei, E, bcnt);
    k_scan_kl<<<2, 1024, 0, stream>>>(bcnt, sbase, bcur,
                                      Wm_mu, Wm_ls, Ws_mu, Ws_ls, okl);
    k_bucket_scatter<<<(E + 4095) / 4096, 256, 0, stream>>>(ei, ew, bcur,
                                                            esrcw, dlo, E);
    k_sub_agg<<<NB3, 256, 0, stream>>>(sbase, esrcw, dlo, pk, bm, bs, om, os, n);
}

// Round 14
// 127.422 us; speedup vs baseline: 1.1880x; 1.1718x over previous
//
#include <hip/hip_runtime.h>
#include <hip/hip_fp16.h>
#include <math.h>

// H = 64, N = 50000 nodes, E = 1.6M edges.
// d_out = [ new_mean (N*64) | new_std (N*64) | total_kl (1) ]
//
// Pipeline:
//   1. k_transform_hist: MFMA h_m = mean@Wm, h_v = (std^2)@Ws -> pk (fp16
//      chunk layout, 256 B/node) + fused 782-bucket histogram of dst>>6.
//   2. k_scan_kl: block 0 = 1024-wide exclusive scan (-> sbase, bcur);
//      block 1 = KL reduction.
//   3. k_bucket_scatter: single-pass, 4096 edges per 256-thr block (391
//      blocks), COARSE buckets (dst>>6, runs ~5.2) and ONE packed 4B record
//      per edge: [d6(31:26) | w10(25:16) | src(15:0)], w10 = top 10 bits of
//      fp16(w) (RNE). Single write stream -> minimal write amplification.
//   4. k_sub_agg: 1564 blocks = (bucket, half); half-bit == record sign bit.
//      Block loads its bucket range into 12 regs, counting-sorts its half
//      into LDS (w10 -> packed (w16<<16|src) words), then the r13 hot loop:
//      wave-per-node register gather-aggregate + fused epilogue.
//
// Lesson log: r10 LDS-atomic accum = 17x regression; r5 forced occupancy =
// spills; r12 98-block scatter = starved; r13 fine-bucket scatter = 86 MB
// write amp (1-byte random streams are poison -> pack to one 4B stream).
//
// ws: bcnt[1024] | sbase[1056] | bcur[1024] | erec uint[E] | pk uint[n*64]
//     (~19.2 MB; ws proven >= 25.6 MB in round 1)

#define NBC  782                 // buckets (dst >> 6), 64 nodes each
#define SCAP 1536                // records per HALF-bucket (mean 1024, ~16 sigma)

typedef _Float16 half8 __attribute__((ext_vector_type(8)));
typedef float f32x4 __attribute__((ext_vector_type(4)));

// MFMA transform + fused histogram (dst>>6).
// Transform: block = 4 waves x 16 nodes = 64 nodes; 16 x mfma_f32_16x16x32_f16.
// A[row=l&15][k=32*kk+8*(l>>4)+j], B[k same][col=l&15] (consistent kappa
// cancels); C/D (HW-verified): col=lane&15, row=(lane>>4)*4+reg.
// pk chunk layout (consumer lane16 = chunk c): t=c&1 (0=mean,1=var), o=c>>1;
// uint j of chunk holds features 8o+2j, 8o+2j+1.
__global__ __launch_bounds__(256) void k_transform_hist(const float* __restrict__ mean,
                                                        const float* __restrict__ stdv,
                                                        const float* __restrict__ Wm,
                                                        const float* __restrict__ Ws,
                                                        uint* __restrict__ pk, int n,
                                                        const int* __restrict__ ei, int E,
                                                        int* __restrict__ bcnt) {
    __shared__ float sW[2 * 4096];
    __shared__ int lh[NBC];
    for (int i = threadIdx.x; i < 4096; i += 256) {
        sW[i] = Wm[i];
        sW[4096 + i] = Ws[i];
    }
    for (int i = threadIdx.x; i < NBC; i += 256) lh[i] = 0;
    __syncthreads();

    for (int t = blockIdx.x * 256 + threadIdx.x; t < E; t += gridDim.x * 256)
        atomicAdd(&lh[ei[E + t] >> 6], 1);
    __syncthreads();
    for (int i = threadIdx.x; i < NBC; i += 256)
        if (lh[i]) atomicAdd(&bcnt[i], lh[i]);

    const int lane = threadIdx.x & 63;
    const int wid  = threadIdx.x >> 6;
    const int l16  = lane & 15;
    const int lg   = lane >> 4;          // 0..3

    half8 bw[2][2][4];
#pragma unroll
    for (int t = 0; t < 2; ++t)
#pragma unroll
        for (int kk = 0; kk < 2; ++kk)
#pragma unroll
            for (int c = 0; c < 4; ++c) {
                half8 h;
#pragma unroll
                for (int j = 0; j < 8; ++j)
                    h[j] = (_Float16)sW[t * 4096 + (32 * kk + 8 * lg + j) * 64 + 16 * c + l16];
                bw[t][kk][c] = h;
            }

    const int nb = blockIdx.x * 64 + wid * 16;
    int arow = nb + l16;
    if (arow >= n) arow = n - 1;         // clamp; rows >= n never stored

    half8 am[2], av[2];
#pragma unroll
    for (int kk = 0; kk < 2; ++kk) {
        const float* mp = mean + (size_t)arow * 64 + 32 * kk + 8 * lg;
        const float* sp = stdv + (size_t)arow * 64 + 32 * kk + 8 * lg;
        float4 m0 = *(const float4*)mp;
        float4 m1 = *(const float4*)(mp + 4);
        float4 s0 = *(const float4*)sp;
        float4 s1 = *(const float4*)(sp + 4);
        half8 a, v;
        a[0] = (_Float16)m0.x; a[1] = (_Float16)m0.y;
        a[2] = (_Float16)m0.z; a[3] = (_Float16)m0.w;
        a[4] = (_Float16)m1.x; a[5] = (_Float16)m1.y;
        a[6] = (_Float16)m1.z; a[7] = (_Float16)m1.w;
        v[0] = (_Float16)(s0.x * s0.x); v[1] = (_Float16)(s0.y * s0.y);
        v[2] = (_Float16)(s0.z * s0.z); v[3] = (_Float16)(s0.w * s0.w);
        v[4] = (_Float16)(s1.x * s1.x); v[5] = (_Float16)(s1.y * s1.y);
        v[6] = (_Float16)(s1.z * s1.z); v[7] = (_Float16)(s1.w * s1.w);
        am[kk] = a; av[kk] = v;
    }

    f32x4 accm[4], accs[4];
    const f32x4 z = {0.f, 0.f, 0.f, 0.f};
#pragma unroll
    for (int c = 0; c < 4; ++c) { accm[c] = z; accs[c] = z; }

#pragma unroll
    for (int c = 0; c < 4; ++c) {
        accm[c] = __builtin_amdgcn_mfma_f32_16x16x32_f16(am[0], bw[0][0][c], accm[c], 0, 0, 0);
        accm[c] = __builtin_amdgcn_mfma_f32_16x16x32_f16(am[1], bw[0][1][c], accm[c], 0, 0, 0);
        accs[c] = __builtin_amdgcn_mfma_f32_16x16x32_f16(av[0], bw[1][0][c], accs[c], 0, 0, 0);
        accs[c] = __builtin_amdgcn_mfma_f32_16x16x32_f16(av[1], bw[1][1][c], accs[c], 0, 0, 0);
    }

#pragma unroll
    for (int c = 0; c < 4; ++c) {
        const int F = 16 * c + l16;
#pragma unroll
        for (int r = 0; r < 4; ++r) {
            int node = nb + 4 * lg + r;
            float mv = accm[c][r];
            float vv = accs[c][r];
            float mp = __shfl_xor(mv, 1, 64);
            float vp = __shfl_xor(vv, 1, 64);
            if (!(l16 & 1) && node < n) {
                int o = F >> 3, j = (F & 7) >> 1;
                __half2 hm = __floats2half2_rn(mv, mp);
                __half2 hv = __floats2half2_rn(vv, vp);
                pk[(size_t)node * 64 + 8 * o + j]     = *reinterpret_cast<uint*>(&hm);
                pk[(size_t)node * 64 + 8 * o + 4 + j] = *reinterpret_cast<uint*>(&hv);
            }
        }
    }
}

// block 0: exclusive scan of bcnt[NBC] -> sbase (incl. sbase[NBC]=E), bcur;
// block 1: KL reduction.
__global__ __launch_bounds__(1024) void k_scan_kl(const int* __restrict__ bcnt,
                                                  int* __restrict__ sbase,
                                                  int* __restrict__ bcur,
                                                  const float* __restrict__ Wm_mu,
                                                  const float* __restrict__ Wm_ls,
                                                  const float* __restrict__ Ws_mu,
                                                  const float* __restrict__ Ws_ls,
                                                  float* __restrict__ okl) {
    if (blockIdx.x == 0) {
        __shared__ int s[1024];
        int v = (threadIdx.x < NBC) ? bcnt[threadIdx.x] : 0;
        s[threadIdx.x] = v;
        __syncthreads();
        for (int off = 1; off < 1024; off <<= 1) {
            int t = 0;
            if (threadIdx.x >= off) t = s[threadIdx.x - off];
            __syncthreads();
            s[threadIdx.x] += t;
            __syncthreads();
        }
        int excl = s[threadIdx.x] - v;
        if (threadIdx.x <= NBC) {
            sbase[threadIdx.x] = excl;       // sbase[NBC] = E
            bcur[threadIdx.x] = excl;
        }
    } else {
        __shared__ float red[1024];
        const float C = -2.3025850929940457f - 0.5f;   // log(0.1) - 0.5
        float acc = 0.f;
        for (int i = threadIdx.x; i < 4096; i += 1024) {
            {
                float mu = Wm_mu[i], ls = Wm_ls[i];
                float s = expf(ls);
                acc += C - ls + (s * s + mu * mu) * 50.0f;  // 1/(2*0.1^2)
            }
            {
                float mu = Ws_mu[i], ls = Ws_ls[i];
                float s = expf(ls);
                acc += C - ls + (s * s + mu * mu) * 50.0f;
            }
        }
        red[threadIdx.x] = acc;
        __syncthreads();
        for (int s = 512; s > 0; s >>= 1) {
            if (threadIdx.x < s) red[threadIdx.x] += red[threadIdx.x + s];
            __syncthreads();
        }
        if (threadIdx.x == 0) okl[0] = red[0];
    }
}

// Single-pass grouping by coarse bucket (dst>>6). 4096 edges per 256-thread
// block (391 blocks); register ranks; ONE packed 4B record per edge:
// [d6(31:26) | w10(25:16) | src(15:0)], w10 = RNE top-10-bits of fp16(w).
__global__ __launch_bounds__(256) void k_bucket_scatter(const int* __restrict__ ei,
                                                        const float* __restrict__ ew,
                                                        int* __restrict__ bcur,
                                                        uint* __restrict__ erec, int E) {
    __shared__ int lcnt[NBC], lpos[NBC];
    for (int i = threadIdx.x; i < NBC; i += 256) lcnt[i] = 0;
    __syncthreads();
    const int base = blockIdx.x * 4096;
    int rr[16];
#pragma unroll
    for (int u = 0; u < 16; ++u) {
        int gi = base + u * 256 + threadIdx.x;
        if (gi < E) rr[u] = atomicAdd(&lcnt[ei[E + gi] >> 6], 1);
    }
    __syncthreads();
    for (int i = threadIdx.x; i < NBC; i += 256)
        lpos[i] = lcnt[i] ? atomicAdd(&bcur[i], lcnt[i]) : 0;
    __syncthreads();
#pragma unroll
    for (int u = 0; u < 16; ++u) {
        int gi = base + u * 256 + threadIdx.x;
        if (gi < E) {
            int d = ei[E + gi];
            uint w16 = (uint)__half_as_ushort(__float2half(ew[gi]));
            uint w10 = (w16 + 16) >> 5;          // RNE to 10 bits (e5m5-ish)
            if (w10 > 1023) w10 = 1023;
            erec[lpos[d >> 6] + rr[u]] =
                ((uint)(d & 63) << 26) | (w10 << 16) | (uint)ei[gi];
        }
    }
}

// Fused filter + local sort + aggregate. Block = (bucket b, half) — half-bit
// is the record sign bit. 256 threads = 4 waves; the block's bucket range is
// loaded once into 12 registers; its half (~1024 records) is counting-sorted
// into LDS as packed (w16<<16|src) words; then the proven hot loop.
__global__ __launch_bounds__(256) void k_sub_agg(const int* __restrict__ sbase,
                                                 const uint* __restrict__ erec,
                                                 const uint* __restrict__ pk,
                                                 const float* __restrict__ bm,
                                                 const float* __restrict__ bs,
                                                 float* __restrict__ om,
                                                 float* __restrict__ os, int nv) {
    __shared__ int ncnt[32], sc[32], noff[33], cur[32];
    __shared__ uint sorted[SCAP];
    const int tid  = threadIdx.x;
    const int b    = blockIdx.x >> 1;
    const uint half = blockIdx.x & 1;
    const int base = sbase[b];
    int cnt = sbase[b + 1] - base;
    if (cnt > 3072) cnt = 3072;          // ~22 sigma, statistically impossible

    uint r[12];
#pragma unroll
    for (int u = 0; u < 12; ++u) {
        int i = u * 256 + tid;
        r[u] = (i < cnt) ? erec[base + i] : 0u;
    }

    if (tid < 32) ncnt[tid] = 0;
    __syncthreads();
#pragma unroll
    for (int u = 0; u < 12; ++u) {
        int i = u * 256 + tid;
        if (i < cnt && (r[u] >> 31) == half)
            atomicAdd(&ncnt[(r[u] >> 26) & 31], 1);
    }
    __syncthreads();
    if (tid < 32) sc[tid] = ncnt[tid];
    __syncthreads();
    for (int off = 1; off < 32; off <<= 1) {
        int t = 0;
        if (tid < 32 && tid >= off) t = sc[tid - off];
        __syncthreads();
        if (tid < 32) sc[tid] += t;
        __syncthreads();
    }
    if (tid < 32) {
        int excl = sc[tid] - ncnt[tid];
        noff[tid] = excl;
        cur[tid] = excl;
        if (tid == 31) noff[32] = sc[31];
    }
    __syncthreads();
#pragma unroll
    for (int u = 0; u < 12; ++u) {
        int i = u * 256 + tid;
        if (i < cnt && (r[u] >> 31) == half) {
            int ln = (r[u] >> 26) & 31;
            int pos = atomicAdd(&cur[ln], 1);
            if (pos < SCAP)
                sorted[pos] = (((r[u] >> 16) & 0x3FFu) << 21) | (r[u] & 0xFFFFu);
        }
    }
    __syncthreads();

    const int lane = tid & 63;
    const int wave = tid >> 6;       // 0..3
    const int g    = lane >> 4;      // edge subgroup 0..3
    const int l16  = lane & 15;      // chunk id: t=l16&1, o=l16>>1
    const int t    = l16 & 1;

    for (int ln = wave * 8; ln < wave * 8 + 8; ++ln) {
        const int node = blockIdx.x * 32 + ln;
        const int st = noff[ln];
        const int cn = noff[ln + 1] - st;

        float accf[8] = {0.f, 0.f, 0.f, 0.f, 0.f, 0.f, 0.f, 0.f};

        for (int be = 0; be < cn; be += 64) {
            int m = cn - be;
            if (m > 64) m = 64;
            uint rec = 0;                          // w16=0 -> w=0.0f
            if (lane < m) rec = sorted[st + be + lane];
            int mr = (m + 31) & ~31;               // 32 or 64

            for (int j0 = 0; j0 < mr; j0 += 32) {
                uint rr[8];
#pragma unroll
                for (int u = 0; u < 8; ++u)
                    rr[u] = (uint)__shfl((int)rec, j0 + 4 * u + g, 64);
                uint4 dd[8];
#pragma unroll
                for (int u = 0; u < 8; ++u)
                    dd[u] = *reinterpret_cast<const uint4*>(
                        pk + (size_t)(rr[u] & 0xFFFFu) * 64 + l16 * 4);
                __half2 wh[8];
#pragma unroll
                for (int u = 0; u < 8; ++u) {
                    float w = __half2float(__ushort_as_half((ushort)(rr[u] >> 16)));
                    float wl = t ? w * w : w;
                    __half h = __float2half(wl);
                    wh[u] = __halves2half2(h, h);
                }
                __half2 a0 = __halves2half2(__half(0.f), __half(0.f));
                __half2 a1 = a0, a2 = a0, a3 = a0;
#pragma unroll
                for (int u = 0; u < 8; ++u) {
                    a0 = __hfma2(*reinterpret_cast<__half2*>(&dd[u].x), wh[u], a0);
                    a1 = __hfma2(*reinterpret_cast<__half2*>(&dd[u].y), wh[u], a1);
                    a2 = __hfma2(*reinterpret_cast<__half2*>(&dd[u].z), wh[u], a2);
                    a3 = __hfma2(*reinterpret_cast<__half2*>(&dd[u].w), wh[u], a3);
                }
                float2 f;
                f = __half22float2(a0); accf[0] += f.x; accf[1] += f.y;
                f = __half22float2(a1); accf[2] += f.x; accf[3] += f.y;
                f = __half22float2(a2); accf[4] += f.x; accf[5] += f.y;
                f = __half22float2(a3); accf[6] += f.x; accf[7] += f.y;
            }
        }

#pragma unroll
        for (int c = 0; c < 8; ++c) {
            accf[c] += __shfl_xor(accf[c], 16, 64);
            accf[c] += __shfl_xor(accf[c], 32, 64);
        }
        // Lane l16 holds accf[c] = aggregated feature 8*(l16>>1)+c of type l16&1.

        if (g == 0 && node < nv) {
            const int f0 = (l16 >> 1) * 8;
            if (!t) {
                float4 b0 = *reinterpret_cast<const float4*>(bm + f0);
                float4 b1 = *reinterpret_cast<const float4*>(bm + f0 + 4);
                float4 r0 = {accf[0] + b0.x, accf[1] + b0.y, accf[2] + b0.z, accf[3] + b0.w};
                float4 r1 = {accf[4] + b1.x, accf[5] + b1.y, accf[6] + b1.z, accf[7] + b1.w};
                *reinterpret_cast<float4*>(om + (size_t)node * 64 + f0)     = r0;
                *reinterpret_cast<float4*>(om + (size_t)node * 64 + f0 + 4) = r1;
            } else {
                float4 b0 = *reinterpret_cast<const float4*>(bs + f0);
                float4 b1 = *reinterpret_cast<const float4*>(bs + f0 + 4);
                float4 r0, r1;
                r0.x = sqrtf(expf(accf[0] + b0.x) + 1e-6f);
                r0.y = sqrtf(expf(accf[1] + b0.y) + 1e-6f);
                r0.z = sqrtf(expf(accf[2] + b0.z) + 1e-6f);
                r0.w = sqrtf(expf(accf[3] + b0.w) + 1e-6f);
                r1.x = sqrtf(expf(accf[4] + b1.x) + 1e-6f);
                r1.y = sqrtf(expf(accf[5] + b1.y) + 1e-6f);
                r1.z = sqrtf(expf(accf[6] + b1.z) + 1e-6f);
                r1.w = sqrtf(expf(accf[7] + b1.w) + 1e-6f);
                *reinterpret_cast<float4*>(os + (size_t)node * 64 + f0)     = r0;
                *reinterpret_cast<float4*>(os + (size_t)node * 64 + f0 + 4) = r1;
            }
        }
    }
}

extern "C" void kernel_launch(void* const* d_in, const int* in_sizes, int n_in,
                              void* d_out, int out_size, void* d_ws, size_t ws_size,
                              hipStream_t stream) {
    const float* mean  = (const float*)d_in[0];
    const float* stdv  = (const float*)d_in[1];
    const int*   ei    = (const int*)d_in[2];
    const float* ew    = (const float*)d_in[3];
    const float* Wm_mu = (const float*)d_in[4];
    const float* Wm_ls = (const float*)d_in[5];
    const float* bm    = (const float*)d_in[6];
    const float* Ws_mu = (const float*)d_in[7];
    const float* Ws_ls = (const float*)d_in[8];
    const float* bs    = (const float*)d_in[9];

    const int n = in_sizes[0] / 64;   // 50000
    const int E = in_sizes[3];        // 1600000
    const int total = n * 64;

    float* om  = (float*)d_out;
    float* os  = om + total;
    float* okl = om + 2 * total;

    char* wsb = (char*)d_ws;
    int* bcnt    = (int*)wsb;                     // 1024
    int* sbase   = bcnt + 1024;                   // 1056
    int* bcur    = sbase + 1056;                  // 1024
    uint* erec   = (uint*)(bcur + 1024);          // E
    size_t pk_off = ((size_t)((char*)(erec + E) - wsb) + 15) & ~(size_t)15;
    uint* pk     = (uint*)(wsb + pk_off);         // total (~19.2 MB overall)

    hipMemsetAsync(bcnt, 0, 1024 * sizeof(int), stream);
    k_transform_hist<<<(n + 63) / 64, 256, 0, stream>>>(mean, stdv, Wm_mu, Ws_mu,
                                                        pk, n, ei, E, bcnt);
    k_scan_kl<<<2, 1024, 0, stream>>>(bcnt, sbase, bcur,
                                      Wm_mu, Wm_ls, Ws_mu, Ws_ls, okl);
    k_bucket_scatter<<<(E + 4095) / 4096, 256, 0, stream>>>(ei, ew, bcur, erec, E);
    k_sub_agg<<<NBC * 2, 256, 0, stream>>>(sbase, erec, pk, bm, bs, om, os, n);
}

// Round 15
// 107.461 us; speedup vs baseline: 1.4087x; 1.1858x over previous
//
#include <hip/hip_runtime.h>
#include <hip/hip_fp16.h>
#include <math.h>

// H = 64, N = 50000 nodes, E = 1.6M edges.
// d_out = [ new_mean (N*64) | new_std (N*64) | total_kl (1) ]
//
// Pipeline (4 kernels, fixed-capacity buckets -> no hist/scan/memset):
//   1. k_init: bcur[i] = i*CAP (one block).
//   2. k_bucket_scatter: single-pass grouping by coarse bucket (dst>>6),
//      4096 edges per 256-thr block, register ranks, packed 4B record
//      [d6(31:26) | w10(25:16) | src(15:0)] into the bucket's CAP region.
//   3. k_transform_kl: MFMA h_m = mean@Wm, h_v = (std^2)@Ws -> pk (fp16
//      chunk layout, 256 B/node); block NTB does the KL reduction instead.
//   4. k_sub_agg: 1564 blocks = (bucket, half) via XCD pair-swizzle (halves
//      of one bucket land on the same XCD for erec L2 reuse); filter by the
//      record's top bit, counting-sort own half into LDS, wave-per-node
//      register gather-aggregate, fused bias + sqrt(exp(x)+1e-6).
//
// Lesson log: r10 LDS-atomic accum = 17x regression; r5 forced occupancy =
// spills; r12 98-block scatter = starved; r13 fine-bucket scatter = 86 MB
// write amp (1-byte random streams are poison); r14 agg is fetch-bound on
// the 12.8 MB random pk gather (~64% L2 hit) — front-end overhead is the
// remaining removable cost.
//
// ws: bcur[1024] | erec uint[NBC*CAP] (9.6 MB) | pk uint[n*64] (12.8 MB)

#define NBC  782                 // buckets (dst >> 6), 64 nodes each
#define CAP  3072                // slots per bucket (mean 2046, ~22 sigma)
#define SCAP 1536                // records per HALF-bucket (mean 1023, ~16 sigma)

typedef _Float16 half8 __attribute__((ext_vector_type(8)));
typedef float f32x4 __attribute__((ext_vector_type(4)));

__global__ __launch_bounds__(1024) void k_init(int* __restrict__ bcur) {
    if (threadIdx.x < NBC) bcur[threadIdx.x] = threadIdx.x * CAP;
}

// Single-pass grouping by coarse bucket (dst>>6). 4096 edges per 256-thread
// block (391 blocks); register ranks; ONE packed 4B record per edge.
__global__ __launch_bounds__(256) void k_bucket_scatter(const int* __restrict__ ei,
                                                        const float* __restrict__ ew,
                                                        int* __restrict__ bcur,
                                                        uint* __restrict__ erec, int E) {
    __shared__ int lcnt[NBC], lpos[NBC];
    for (int i = threadIdx.x; i < NBC; i += 256) lcnt[i] = 0;
    __syncthreads();
    const int base = blockIdx.x * 4096;
    int rr[16];
#pragma unroll
    for (int u = 0; u < 16; ++u) {
        int gi = base + u * 256 + threadIdx.x;
        if (gi < E) rr[u] = atomicAdd(&lcnt[ei[E + gi] >> 6], 1);
    }
    __syncthreads();
    for (int i = threadIdx.x; i < NBC; i += 256)
        lpos[i] = lcnt[i] ? atomicAdd(&bcur[i], lcnt[i]) : 0;
    __syncthreads();
#pragma unroll
    for (int u = 0; u < 16; ++u) {
        int gi = base + u * 256 + threadIdx.x;
        if (gi < E) {
            int d = ei[E + gi];
            uint w16 = (uint)__half_as_ushort(__float2half(ew[gi]));
            uint w10 = (w16 + 16) >> 5;          // RNE to 10 bits
            if (w10 > 1023) w10 = 1023;
            erec[lpos[d >> 6] + rr[u]] =
                ((uint)(d & 63) << 26) | (w10 << 16) | (uint)ei[gi];
        }
    }
}

// MFMA transform (blocks 0..NTB-1) + KL reduction (block NTB).
// Transform: block = 4 waves x 16 nodes = 64 nodes; 16 x mfma_f32_16x16x32_f16.
// A[row=l&15][k=32*kk+8*(l>>4)+j], B[k same][col=l&15] (consistent kappa
// cancels); C/D (HW-verified): col=lane&15, row=(lane>>4)*4+reg.
// pk chunk layout (consumer lane16 = chunk c): t=c&1 (0=mean,1=var), o=c>>1;
// uint j of chunk holds features 8o+2j, 8o+2j+1.
__global__ __launch_bounds__(256) void k_transform_kl(const float* __restrict__ mean,
                                                      const float* __restrict__ stdv,
                                                      const float* __restrict__ Wm,
                                                      const float* __restrict__ Ws,
                                                      uint* __restrict__ pk, int n, int ntb,
                                                      const float* __restrict__ Wm_ls,
                                                      const float* __restrict__ Ws_ls,
                                                      float* __restrict__ okl) {
    if ((int)blockIdx.x == ntb) {
        // KL( N(mu,sigma) || N(0,0.1) ) summed over both weight matrices.
        __shared__ float red[256];
        const float C = -2.3025850929940457f - 0.5f;   // log(0.1) - 0.5
        float acc = 0.f;
        for (int i = threadIdx.x; i < 4096; i += 256) {
            {
                float mu = Wm[i], ls = Wm_ls[i];
                float s = expf(ls);
                acc += C - ls + (s * s + mu * mu) * 50.0f;  // 1/(2*0.1^2)
            }
            {
                float mu = Ws[i], ls = Ws_ls[i];
                float s = expf(ls);
                acc += C - ls + (s * s + mu * mu) * 50.0f;
            }
        }
        red[threadIdx.x] = acc;
        __syncthreads();
        for (int s = 128; s > 0; s >>= 1) {
            if (threadIdx.x < s) red[threadIdx.x] += red[threadIdx.x + s];
            __syncthreads();
        }
        if (threadIdx.x == 0) okl[0] = red[0];
        return;
    }

    __shared__ float sW[2 * 4096];
    for (int i = threadIdx.x; i < 4096; i += 256) {
        sW[i] = Wm[i];
        sW[4096 + i] = Ws[i];
    }
    __syncthreads();

    const int lane = threadIdx.x & 63;
    const int wid  = threadIdx.x >> 6;
    const int l16  = lane & 15;
    const int lg   = lane >> 4;          // 0..3

    half8 bw[2][2][4];
#pragma unroll
    for (int t = 0; t < 2; ++t)
#pragma unroll
        for (int kk = 0; kk < 2; ++kk)
#pragma unroll
            for (int c = 0; c < 4; ++c) {
                half8 h;
#pragma unroll
                for (int j = 0; j < 8; ++j)
                    h[j] = (_Float16)sW[t * 4096 + (32 * kk + 8 * lg + j) * 64 + 16 * c + l16];
                bw[t][kk][c] = h;
            }

    const int nb = blockIdx.x * 64 + wid * 16;
    int arow = nb + l16;
    if (arow >= n) arow = n - 1;         // clamp; rows >= n never stored

    half8 am[2], av[2];
#pragma unroll
    for (int kk = 0; kk < 2; ++kk) {
        const float* mp = mean + (size_t)arow * 64 + 32 * kk + 8 * lg;
        const float* sp = stdv + (size_t)arow * 64 + 32 * kk + 8 * lg;
        float4 m0 = *(const float4*)mp;
        float4 m1 = *(const float4*)(mp + 4);
        float4 s0 = *(const float4*)sp;
        float4 s1 = *(const float4*)(sp + 4);
        half8 a, v;
        a[0] = (_Float16)m0.x; a[1] = (_Float16)m0.y;
        a[2] = (_Float16)m0.z; a[3] = (_Float16)m0.w;
        a[4] = (_Float16)m1.x; a[5] = (_Float16)m1.y;
        a[6] = (_Float16)m1.z; a[7] = (_Float16)m1.w;
        v[0] = (_Float16)(s0.x * s0.x); v[1] = (_Float16)(s0.y * s0.y);
        v[2] = (_Float16)(s0.z * s0.z); v[3] = (_Float16)(s0.w * s0.w);
        v[4] = (_Float16)(s1.x * s1.x); v[5] = (_Float16)(s1.y * s1.y);
        v[6] = (_Float16)(s1.z * s1.z); v[7] = (_Float16)(s1.w * s1.w);
        am[kk] = a; av[kk] = v;
    }

    f32x4 accm[4], accs[4];
    const f32x4 z = {0.f, 0.f, 0.f, 0.f};
#pragma unroll
    for (int c = 0; c < 4; ++c) { accm[c] = z; accs[c] = z; }

#pragma unroll
    for (int c = 0; c < 4; ++c) {
        accm[c] = __builtin_amdgcn_mfma_f32_16x16x32_f16(am[0], bw[0][0][c], accm[c], 0, 0, 0);
        accm[c] = __builtin_amdgcn_mfma_f32_16x16x32_f16(am[1], bw[0][1][c], accm[c], 0, 0, 0);
        accs[c] = __builtin_amdgcn_mfma_f32_16x16x32_f16(av[0], bw[1][0][c], accs[c], 0, 0, 0);
        accs[c] = __builtin_amdgcn_mfma_f32_16x16x32_f16(av[1], bw[1][1][c], accs[c], 0, 0, 0);
    }

#pragma unroll
    for (int c = 0; c < 4; ++c) {
        const int F = 16 * c + l16;
#pragma unroll
        for (int r = 0; r < 4; ++r) {
            int node = nb + 4 * lg + r;
            float mv = accm[c][r];
            float vv = accs[c][r];
            float mp = __shfl_xor(mv, 1, 64);
            float vp = __shfl_xor(vv, 1, 64);
            if (!(l16 & 1) && node < n) {
                int o = F >> 3, j = (F & 7) >> 1;
                __half2 hm = __floats2half2_rn(mv, mp);
                __half2 hv = __floats2half2_rn(vv, vp);
                pk[(size_t)node * 64 + 8 * o + j]     = *reinterpret_cast<uint*>(&hm);
                pk[(size_t)node * 64 + 8 * o + 4 + j] = *reinterpret_cast<uint*>(&hv);
            }
        }
    }
}

// Fused filter + local sort + aggregate. Launch index L -> (pair, half) so
// that both halves of a bucket are 8 apart (same XCD under round-robin
// dispatch) for erec L2 reuse. 256 threads = 4 waves.
__global__ __launch_bounds__(256) void k_sub_agg(const int* __restrict__ bcur,
                                                 const uint* __restrict__ erec,
                                                 const uint* __restrict__ pk,
                                                 const float* __restrict__ bm,
                                                 const float* __restrict__ bs,
                                                 float* __restrict__ om,
                                                 float* __restrict__ os, int nv) {
    __shared__ int ncnt[32], sc[32], noff[33], cur[32];
    __shared__ uint sorted[SCAP];
    const int tid = threadIdx.x;

    // pair swizzle: L and L+8 (same XCD) are the two halves of one bucket.
    int L = blockIdx.x;
    int b, half;
    if (L < 1552) { b = (L >> 4) * 8 + (L & 7); half = (L >> 3) & 1; }
    else          { int t2 = L - 1552; b = 776 + (t2 >> 1); half = t2 & 1; }

    const int base = b * CAP;
    int cnt = bcur[b] - base;
    if (cnt > CAP) cnt = CAP;            // statistically impossible

    uint r[12];
#pragma unroll
    for (int u = 0; u < 12; ++u) {
        int i = u * 256 + tid;
        r[u] = (i < cnt) ? erec[base + i] : 0u;
    }

    if (tid < 32) ncnt[tid] = 0;
    __syncthreads();
#pragma unroll
    for (int u = 0; u < 12; ++u) {
        int i = u * 256 + tid;
        if (i < cnt && (int)(r[u] >> 31) == half)
            atomicAdd(&ncnt[(r[u] >> 26) & 31], 1);
    }
    __syncthreads();
    if (tid < 32) sc[tid] = ncnt[tid];
    __syncthreads();
    for (int off = 1; off < 32; off <<= 1) {
        int t = 0;
        if (tid < 32 && tid >= off) t = sc[tid - off];
        __syncthreads();
        if (tid < 32) sc[tid] += t;
        __syncthreads();
    }
    if (tid < 32) {
        int excl = sc[tid] - ncnt[tid];
        noff[tid] = excl;
        cur[tid] = excl;
        if (tid == 31) noff[32] = sc[31];
    }
    __syncthreads();
#pragma unroll
    for (int u = 0; u < 12; ++u) {
        int i = u * 256 + tid;
        if (i < cnt && (int)(r[u] >> 31) == half) {
            int ln = (r[u] >> 26) & 31;
            int pos = atomicAdd(&cur[ln], 1);
            if (pos < SCAP)
                sorted[pos] = (((r[u] >> 16) & 0x3FFu) << 21) | (r[u] & 0xFFFFu);
        }
    }
    __syncthreads();

    const int lane = tid & 63;
    const int wave = tid >> 6;       // 0..3
    const int g    = lane >> 4;      // edge subgroup 0..3
    const int l16  = lane & 15;      // chunk id: t=l16&1, o=l16>>1
    const int t    = l16 & 1;

    for (int ln = wave * 8; ln < wave * 8 + 8; ++ln) {
        const int node = b * 64 + half * 32 + ln;
        const int st = noff[ln];
        const int cn = noff[ln + 1] - st;

        float accf[8] = {0.f, 0.f, 0.f, 0.f, 0.f, 0.f, 0.f, 0.f};

        for (int be = 0; be < cn; be += 64) {
            int m = cn - be;
            if (m > 64) m = 64;
            uint rec = 0;                          // w16=0 -> w=0.0f
            if (lane < m) rec = sorted[st + be + lane];
            int mr = (m + 31) & ~31;               // 32 or 64

            for (int j0 = 0; j0 < mr; j0 += 32) {
                uint rr[8];
#pragma unroll
                for (int u = 0; u < 8; ++u)
                    rr[u] = (uint)__shfl((int)rec, j0 + 4 * u + g, 64);
                uint4 dd[8];
#pragma unroll
                for (int u = 0; u < 8; ++u)
                    dd[u] = *reinterpret_cast<const uint4*>(
                        pk + (size_t)(rr[u] & 0xFFFFu) * 64 + l16 * 4);
                __half2 wh[8];
#pragma unroll
                for (int u = 0; u < 8; ++u) {
                    float w = __half2float(__ushort_as_half((ushort)(rr[u] >> 16)));
                    float wl = t ? w * w : w;
                    __half h = __float2half(wl);
                    wh[u] = __halves2half2(h, h);
                }
                __half2 a0 = __halves2half2(__half(0.f), __half(0.f));
                __half2 a1 = a0, a2 = a0, a3 = a0;
#pragma unroll
                for (int u = 0; u < 8; ++u) {
                    a0 = __hfma2(*reinterpret_cast<__half2*>(&dd[u].x), wh[u], a0);
                    a1 = __hfma2(*reinterpret_cast<__half2*>(&dd[u].y), wh[u], a1);
                    a2 = __hfma2(*reinterpret_cast<__half2*>(&dd[u].z), wh[u], a2);
                    a3 = __hfma2(*reinterpret_cast<__half2*>(&dd[u].w), wh[u], a3);
                }
                float2 f;
                f = __half22float2(a0); accf[0] += f.x; accf[1] += f.y;
                f = __half22float2(a1); accf[2] += f.x; accf[3] += f.y;
                f = __half22float2(a2); accf[4] += f.x; accf[5] += f.y;
                f = __half22float2(a3); accf[6] += f.x; accf[7] += f.y;
            }
        }

#pragma unroll
        for (int c = 0; c < 8; ++c) {
            accf[c] += __shfl_xor(accf[c], 16, 64);
            accf[c] += __shfl_xor(accf[c], 32, 64);
        }
        // Lane l16 holds accf[c] = aggregated feature 8*(l16>>1)+c of type l16&1.

        if (g == 0 && node < nv) {
            const int f0 = (l16 >> 1) * 8;
            if (!t) {
                float4 b0 = *reinterpret_cast<const float4*>(bm + f0);
                float4 b1 = *reinterpret_cast<const float4*>(bm + f0 + 4);
                float4 r0 = {accf[0] + b0.x, accf[1] + b0.y, accf[2] + b0.z, accf[3] + b0.w};
                float4 r1 = {accf[4] + b1.x, accf[5] + b1.y, accf[6] + b1.z, accf[7] + b1.w};
                *reinterpret_cast<float4*>(om + (size_t)node * 64 + f0)     = r0;
                *reinterpret_cast<float4*>(om + (size_t)node * 64 + f0 + 4) = r1;
            } else {
                float4 b0 = *reinterpret_cast<const float4*>(bs + f0);
                float4 b1 = *reinterpret_cast<const float4*>(bs + f0 + 4);
                float4 r0, r1;
                r0.x = sqrtf(expf(accf[0] + b0.x) + 1e-6f);
                r0.y = sqrtf(expf(accf[1] + b0.y) + 1e-6f);
                r0.z = sqrtf(expf(accf[2] + b0.z) + 1e-6f);
                r0.w = sqrtf(expf(accf[3] + b0.w) + 1e-6f);
                r1.x = sqrtf(expf(accf[4] + b1.x) + 1e-6f);
                r1.y = sqrtf(expf(accf[5] + b1.y) + 1e-6f);
                r1.z = sqrtf(expf(accf[6] + b1.z) + 1e-6f);
                r1.w = sqrtf(expf(accf[7] + b1.w) + 1e-6f);
                *reinterpret_cast<float4*>(os + (size_t)node * 64 + f0)     = r0;
                *reinterpret_cast<float4*>(os + (size_t)node * 64 + f0 + 4) = r1;
            }
        }
    }
}

extern "C" void kernel_launch(void* const* d_in, const int* in_sizes, int n_in,
                              void* d_out, int out_size, void* d_ws, size_t ws_size,
                              hipStream_t stream) {
    const float* mean  = (const float*)d_in[0];
    const float* stdv  = (const float*)d_in[1];
    const int*   ei    = (const int*)d_in[2];
    const float* ew    = (const float*)d_in[3];
    const float* Wm_mu = (const float*)d_in[4];
    const float* Wm_ls = (const float*)d_in[5];
    const float* bm    = (const float*)d_in[6];
    const float* Ws_mu = (const float*)d_in[7];
    const float* Ws_ls = (const float*)d_in[8];
    const float* bs    = (const float*)d_in[9];

    const int n = in_sizes[0] / 64;   // 50000
    const int E = in_sizes[3];        // 1600000
    const int total = n * 64;

    float* om  = (float*)d_out;
    float* os  = om + total;
    float* okl = om + 2 * total;

    char* wsb = (char*)d_ws;
    int* bcur    = (int*)wsb;                     // 1024
    uint* erec   = (uint*)(bcur + 1024);          // NBC*CAP (9.6 MB)
    size_t pk_off = ((size_t)((char*)(erec + NBC * CAP) - wsb) + 15) & ~(size_t)15;
    uint* pk     = (uint*)(wsb + pk_off);         // n*64 (12.8 MB)

    const int ntb = (n + 63) / 64;    // 782 transform blocks

    k_init<<<1, 1024, 0, stream>>>(bcur);
    k_bucket_scatter<<<(E + 4095) / 4096, 256, 0, stream>>>(ei, ew, bcur, erec, E);
    k_transform_kl<<<ntb + 1, 256, 0, stream>>>(mean, stdv, Wm_mu, Ws_mu, pk, n, ntb,
                                                Wm_ls, Ws_ls, okl);
    k_sub_agg<<<NBC * 2, 256, 0, stream>>>(bcur, erec, pk, bm, bs, om, os, n);
}

// Round 16
// 97.618 us; speedup vs baseline: 1.5507x; 1.1008x over previous
//
#include <hip/hip_runtime.h>
#include <hip/hip_fp16.h>
#include <math.h>

// H = 64, N = 50000 nodes, E = 1.6M edges.
// d_out = [ new_mean (N*64) | new_std (N*64) | total_kl (1) ]
//
// Pipeline (3 kernels):
//   1. k_init: bcur[i] = i*CAP.
//   2. k_front (block-range dispatch, 32 KB aliased LDS):
//      blocks [0,NSB):    scatter into fixed-CAP coarse buckets (dst>>6),
//                         packed 4B record [d6|w10|src16]
//      blocks [NSB,+NTB): MFMA transform h_m = mean@Wm, h_v = (std^2)@Ws
//                         -> pk fp16 chunk layout (256 B/node)
//      last block:        KL reduction
//      Scatter blocks are memory-stall-bound, transform blocks VALU/MFMA-
//      bound -> co-running overlaps the pipes.
//   3. k_sub_agg: 1564 blocks = (bucket, half) with XCD pair-swizzle;
//      filter own half, counting-sort into LDS as uint2{half2(w,w2), src}
//      with per-node regions PADDED to 32 and pre-zeroed (free tails);
//      hot loop: broadcast ds_read_b64 + 16B pk gather + hfma2, no shfl;
//      fused bias + sqrt(exp(x)+1e-6) epilogue.
//
// Lesson log: r10 LDS-atomic accum = 17x; r5 VGPR cap = spills; r12 98-blk
// scatter = starved; r13 byte-stream scatter = 86 MB write amp; r15 front-end
// was 35% of runtime serialized -> merge; weight unpack was 16x redundant
// across lanes -> precompute at sort.
//
// ws: bcur[1024] | erec uint[NBC*CAP] (9.6 MB) | pk uint[n*64] (12.8 MB)

#define NBC   782                // buckets (dst >> 6), 64 nodes each
#define CAP   3072               // slots per bucket (mean 2046, ~22 sigma)
#define SCAP2 2304               // sorted capacity per half (padded; ~12 sigma)

typedef _Float16 half8 __attribute__((ext_vector_type(8)));
typedef float f32x4 __attribute__((ext_vector_type(4)));

__global__ __launch_bounds__(1024) void k_init(int* __restrict__ bcur) {
    if (threadIdx.x < NBC) bcur[threadIdx.x] = threadIdx.x * CAP;
}

// Merged front-end. smem aliased per block role.
__global__ __launch_bounds__(256) void k_front(const int* __restrict__ ei,
                                               const float* __restrict__ ew,
                                               int* __restrict__ bcur,
                                               uint* __restrict__ erec, int E,
                                               const float* __restrict__ mean,
                                               const float* __restrict__ stdv,
                                               const float* __restrict__ Wm,
                                               const float* __restrict__ Ws,
                                               uint* __restrict__ pk, int n,
                                               int nsb, int ntb,
                                               const float* __restrict__ Wm_ls,
                                               const float* __restrict__ Ws_ls,
                                               float* __restrict__ okl) {
    __shared__ uint smem[8192];   // 32 KB, aliased
    const int bid = blockIdx.x;

    if (bid < nsb) {
        // ---- scatter: 4096 edges, register ranks, one packed 4B record ----
        int* lcnt = (int*)smem;
        int* lpos = lcnt + NBC;
        for (int i = threadIdx.x; i < NBC; i += 256) lcnt[i] = 0;
        __syncthreads();
        const int base = bid * 4096;
        int rr[16];
#pragma unroll
        for (int u = 0; u < 16; ++u) {
            int gi = base + u * 256 + threadIdx.x;
            if (gi < E) rr[u] = atomicAdd(&lcnt[ei[E + gi] >> 6], 1);
        }
        __syncthreads();
        for (int i = threadIdx.x; i < NBC; i += 256)
            lpos[i] = lcnt[i] ? atomicAdd(&bcur[i], lcnt[i]) : 0;
        __syncthreads();
#pragma unroll
        for (int u = 0; u < 16; ++u) {
            int gi = base + u * 256 + threadIdx.x;
            if (gi < E) {
                int d = ei[E + gi];
                uint w16 = (uint)__half_as_ushort(__float2half(ew[gi]));
                uint w10 = (w16 + 16) >> 5;          // RNE to 10 bits
                if (w10 > 1023) w10 = 1023;
                erec[lpos[d >> 6] + rr[u]] =
                    ((uint)(d & 63) << 26) | (w10 << 16) | (uint)ei[gi];
            }
        }
        return;
    }

    if (bid == nsb + ntb) {
        // ---- KL reduction ----
        float* red = (float*)smem;
        const float C = -2.3025850929940457f - 0.5f;   // log(0.1) - 0.5
        float acc = 0.f;
        for (int i = threadIdx.x; i < 4096; i += 256) {
            {
                float mu = Wm[i], ls = Wm_ls[i];
                float s = expf(ls);
                acc += C - ls + (s * s + mu * mu) * 50.0f;  // 1/(2*0.1^2)
            }
            {
                float mu = Ws[i], ls = Ws_ls[i];
                float s = expf(ls);
                acc += C - ls + (s * s + mu * mu) * 50.0f;
            }
        }
        red[threadIdx.x] = acc;
        __syncthreads();
        for (int s = 128; s > 0; s >>= 1) {
            if (threadIdx.x < s) red[threadIdx.x] += red[threadIdx.x + s];
            __syncthreads();
        }
        if (threadIdx.x == 0) okl[0] = red[0];
        return;
    }

    // ---- MFMA transform: block = 4 waves x 16 nodes = 64 nodes ----
    // A[row=l&15][k=32*kk+8*(l>>4)+j], B[k same][col=l&15] (consistent kappa
    // cancels); C/D (HW-verified): col=lane&15, row=(lane>>4)*4+reg.
    // pk chunk layout (consumer lane16 = chunk c): t=c&1, o=c>>1;
    // uint j of chunk holds features 8o+2j, 8o+2j+1.
    float* sW = (float*)smem;
    for (int i = threadIdx.x; i < 4096; i += 256) {
        sW[i] = Wm[i];
        sW[4096 + i] = Ws[i];
    }
    __syncthreads();

    const int lane = threadIdx.x & 63;
    const int wid  = threadIdx.x >> 6;
    const int l16  = lane & 15;
    const int lg   = lane >> 4;          // 0..3

    half8 bw[2][2][4];
#pragma unroll
    for (int t = 0; t < 2; ++t)
#pragma unroll
        for (int kk = 0; kk < 2; ++kk)
#pragma unroll
            for (int c = 0; c < 4; ++c) {
                half8 h;
#pragma unroll
                for (int j = 0; j < 8; ++j)
                    h[j] = (_Float16)sW[t * 4096 + (32 * kk + 8 * lg + j) * 64 + 16 * c + l16];
                bw[t][kk][c] = h;
            }

    const int nb = (bid - nsb) * 64 + wid * 16;
    int arow = nb + l16;
    if (arow >= n) arow = n - 1;         // clamp; rows >= n never stored

    half8 am[2], av[2];
#pragma unroll
    for (int kk = 0; kk < 2; ++kk) {
        const float* mp = mean + (size_t)arow * 64 + 32 * kk + 8 * lg;
        const float* sp = stdv + (size_t)arow * 64 + 32 * kk + 8 * lg;
        float4 m0 = *(const float4*)mp;
        float4 m1 = *(const float4*)(mp + 4);
        float4 s0 = *(const float4*)sp;
        float4 s1 = *(const float4*)(sp + 4);
        half8 a, v;
        a[0] = (_Float16)m0.x; a[1] = (_Float16)m0.y;
        a[2] = (_Float16)m0.z; a[3] = (_Float16)m0.w;
        a[4] = (_Float16)m1.x; a[5] = (_Float16)m1.y;
        a[6] = (_Float16)m1.z; a[7] = (_Float16)m1.w;
        v[0] = (_Float16)(s0.x * s0.x); v[1] = (_Float16)(s0.y * s0.y);
        v[2] = (_Float16)(s0.z * s0.z); v[3] = (_Float16)(s0.w * s0.w);
        v[4] = (_Float16)(s1.x * s1.x); v[5] = (_Float16)(s1.y * s1.y);
        v[6] = (_Float16)(s1.z * s1.z); v[7] = (_Float16)(s1.w * s1.w);
        am[kk] = a; av[kk] = v;
    }

    f32x4 accm[4], accs[4];
    const f32x4 z = {0.f, 0.f, 0.f, 0.f};
#pragma unroll
    for (int c = 0; c < 4; ++c) { accm[c] = z; accs[c] = z; }

#pragma unroll
    for (int c = 0; c < 4; ++c) {
        accm[c] = __builtin_amdgcn_mfma_f32_16x16x32_f16(am[0], bw[0][0][c], accm[c], 0, 0, 0);
        accm[c] = __builtin_amdgcn_mfma_f32_16x16x32_f16(am[1], bw[0][1][c], accm[c], 0, 0, 0);
        accs[c] = __builtin_amdgcn_mfma_f32_16x16x32_f16(av[0], bw[1][0][c], accs[c], 0, 0, 0);
        accs[c] = __builtin_amdgcn_mfma_f32_16x16x32_f16(av[1], bw[1][1][c], accs[c], 0, 0, 0);
    }

#pragma unroll
    for (int c = 0; c < 4; ++c) {
        const int F = 16 * c + l16;
#pragma unroll
        for (int r = 0; r < 4; ++r) {
            int node = nb + 4 * lg + r;
            float mv = accm[c][r];
            float vv = accs[c][r];
            float mp = __shfl_xor(mv, 1, 64);
            float vp = __shfl_xor(vv, 1, 64);
            if (!(l16 & 1) && node < n) {
                int o = F >> 3, j = (F & 7) >> 1;
                __half2 hm = __floats2half2_rn(mv, mp);
                __half2 hv = __floats2half2_rn(vv, vp);
                pk[(size_t)node * 64 + 8 * o + j]     = *reinterpret_cast<uint*>(&hm);
                pk[(size_t)node * 64 + 8 * o + 4 + j] = *reinterpret_cast<uint*>(&hv);
            }
        }
    }
}

// Fused filter + padded counting sort + aggregate.
// Block L -> (bucket, half) pair-swizzled so both halves share an XCD.
__global__ __launch_bounds__(256) void k_sub_agg(const int* __restrict__ bcur,
                                                 const uint* __restrict__ erec,
                                                 const uint* __restrict__ pk,
                                                 const float* __restrict__ bm,
                                                 const float* __restrict__ bs,
                                                 float* __restrict__ om,
                                                 float* __restrict__ os, int nv) {
    __shared__ int ncnt[32], sc[32], noff[33], cur[32];
    __shared__ uint2 sorted[SCAP2];     // {half2(w,w^2), src}
    const int tid = threadIdx.x;

    // pair swizzle: L and L+8 (same XCD) are the two halves of one bucket.
    int L = blockIdx.x;
    int b, half;
    if (L < 1552) { b = (L >> 4) * 8 + (L & 7); half = (L >> 3) & 1; }
    else          { int t2 = L - 1552; b = 776 + (t2 >> 1); half = t2 & 1; }

    const int base = b * CAP;
    int cnt = bcur[b] - base;
    if (cnt > CAP) cnt = CAP;            // statistically impossible

    for (int i = tid; i < SCAP2; i += 256) sorted[i] = make_uint2(0u, 0u);

    uint r[12];
#pragma unroll
    for (int u = 0; u < 12; ++u) {
        int i = u * 256 + tid;
        r[u] = (i < cnt) ? erec[base + i] : 0u;
    }

    if (tid < 32) ncnt[tid] = 0;
    __syncthreads();
#pragma unroll
    for (int u = 0; u < 12; ++u) {
        int i = u * 256 + tid;
        if (i < cnt && (int)(r[u] >> 31) == half)
            atomicAdd(&ncnt[(r[u] >> 26) & 31], 1);
    }
    __syncthreads();
    if (tid < 32) sc[tid] = (ncnt[tid] + 31) & ~31;   // padded counts
    __syncthreads();
    for (int off = 1; off < 32; off <<= 1) {
        int t = 0;
        if (tid < 32 && tid >= off) t = sc[tid - off];
        __syncthreads();
        if (tid < 32) sc[tid] += t;
        __syncthreads();
    }
    if (tid < 32) {
        int excl = sc[tid] - ((ncnt[tid] + 31) & ~31);
        noff[tid] = excl;
        cur[tid] = excl;
        if (tid == 31) noff[32] = sc[31];
    }
    __syncthreads();
#pragma unroll
    for (int u = 0; u < 12; ++u) {
        int i = u * 256 + tid;
        if (i < cnt && (int)(r[u] >> 31) == half) {
            int ln = (r[u] >> 26) & 31;
            int pos = atomicAdd(&cur[ln], 1);
            uint w10 = (r[u] >> 16) & 0x3FFu;
            float wf = __half2float(__ushort_as_half((ushort)(w10 << 5)));
            __half2 wp = __floats2half2_rn(wf, wf * wf);
            if (pos < SCAP2)
                sorted[pos] = make_uint2(*reinterpret_cast<uint*>(&wp),
                                         r[u] & 0xFFFFu);
        }
    }
    __syncthreads();

    const int lane = tid & 63;
    const int wave = tid >> 6;       // 0..3
    const int g    = lane >> 4;      // edge subgroup 0..3
    const int l16  = lane & 15;      // chunk id: t=l16&1, o=l16>>1
    const int tsh  = (l16 & 1) << 4; // select w (t=0) or w^2 (t=1)

    for (int ln = wave * 8; ln < wave * 8 + 8; ++ln) {
        const int node = b * 64 + half * 32 + ln;
        const int st  = noff[ln];
        const int pcn = noff[ln + 1] - st;   // padded multiple of 32 (tails are 0-weight)

        float accf[8] = {0.f, 0.f, 0.f, 0.f, 0.f, 0.f, 0.f, 0.f};

        for (int j0 = 0; j0 < pcn; j0 += 32) {
            uint4 dd[8];
            uint  wx[8];
#pragma unroll
            for (int u = 0; u < 8; ++u) {
                uint2 e = sorted[st + j0 + 4 * u + g];
                wx[u] = e.x;
                dd[u] = *reinterpret_cast<const uint4*>(
                    pk + (size_t)e.y * 64 + l16 * 4);
            }
            __half2 a0 = __halves2half2(__half(0.f), __half(0.f));
            __half2 a1 = a0, a2 = a0, a3 = a0;
#pragma unroll
            for (int u = 0; u < 8; ++u) {
                uint hsel = (wx[u] >> tsh) & 0xFFFFu;
                uint whb = (hsel << 16) | hsel;
                __half2 wh = *reinterpret_cast<__half2*>(&whb);
                a0 = __hfma2(*reinterpret_cast<__half2*>(&dd[u].x), wh, a0);
                a1 = __hfma2(*reinterpret_cast<__half2*>(&dd[u].y), wh, a1);
                a2 = __hfma2(*reinterpret_cast<__half2*>(&dd[u].z), wh, a2);
                a3 = __hfma2(*reinterpret_cast<__half2*>(&dd[u].w), wh, a3);
            }
            float2 f;
            f = __half22float2(a0); accf[0] += f.x; accf[1] += f.y;
            f = __half22float2(a1); accf[2] += f.x; accf[3] += f.y;
            f = __half22float2(a2); accf[4] += f.x; accf[5] += f.y;
            f = __half22float2(a3); accf[6] += f.x; accf[7] += f.y;
        }

#pragma unroll
        for (int c = 0; c < 8; ++c) {
            accf[c] += __shfl_xor(accf[c], 16, 64);
            accf[c] += __shfl_xor(accf[c], 32, 64);
        }
        // Lane l16 holds accf[c] = aggregated feature 8*(l16>>1)+c of type l16&1.

        if (g == 0 && node < nv) {
            const int f0 = (l16 >> 1) * 8;
            if (!(l16 & 1)) {
                float4 b0 = *reinterpret_cast<const float4*>(bm + f0);
                float4 b1 = *reinterpret_cast<const float4*>(bm + f0 + 4);
                float4 r0 = {accf[0] + b0.x, accf[1] + b0.y, accf[2] + b0.z, accf[3] + b0.w};
                float4 r1 = {accf[4] + b1.x, accf[5] + b1.y, accf[6] + b1.z, accf[7] + b1.w};
                *reinterpret_cast<float4*>(om + (size_t)node * 64 + f0)     = r0;
                *reinterpret_cast<float4*>(om + (size_t)node * 64 + f0 + 4) = r1;
            } else {
                float4 b0 = *reinterpret_cast<const float4*>(bs + f0);
                float4 b1 = *reinterpret_cast<const float4*>(bs + f0 + 4);
                float4 r0, r1;
                r0.x = sqrtf(expf(accf[0] + b0.x) + 1e-6f);
                r0.y = sqrtf(expf(accf[1] + b0.y) + 1e-6f);
                r0.z = sqrtf(expf(accf[2] + b0.z) + 1e-6f);
                r0.w = sqrtf(expf(accf[3] + b0.w) + 1e-6f);
                r1.x = sqrtf(expf(accf[4] + b1.x) + 1e-6f);
                r1.y = sqrtf(expf(accf[5] + b1.y) + 1e-6f);
                r1.z = sqrtf(expf(accf[6] + b1.z) + 1e-6f);
                r1.w = sqrtf(expf(accf[7] + b1.w) + 1e-6f);
                *reinterpret_cast<float4*>(os + (size_t)node * 64 + f0)     = r0;
                *reinterpret_cast<float4*>(os + (size_t)node * 64 + f0 + 4) = r1;
            }
        }
    }
}

extern "C" void kernel_launch(void* const* d_in, const int* in_sizes, int n_in,
                              void* d_out, int out_size, void* d_ws, size_t ws_size,
                              hipStream_t stream) {
    const float* mean  = (const float*)d_in[0];
    const float* stdv  = (const float*)d_in[1];
    const int*   ei    = (const int*)d_in[2];
    const float* ew    = (const float*)d_in[3];
    const float* Wm_mu = (const float*)d_in[4];
    const float* Wm_ls = (const float*)d_in[5];
    const float* bm    = (const float*)d_in[6];
    const float* Ws_mu = (const float*)d_in[7];
    const float* Ws_ls = (const float*)d_in[8];
    const float* bs    = (const float*)d_in[9];

    const int n = in_sizes[0] / 64;   // 50000
    const int E = in_sizes[3];        // 1600000
    const int total = n * 64;

    float* om  = (float*)d_out;
    float* os  = om + total;
    float* okl = om + 2 * total;

    char* wsb = (char*)d_ws;
    int* bcur    = (int*)wsb;                     // 1024
    uint* erec   = (uint*)(bcur + 1024);          // NBC*CAP (9.6 MB)
    size_t pk_off = ((size_t)((char*)(erec + NBC * CAP) - wsb) + 15) & ~(size_t)15;
    uint* pk     = (uint*)(wsb + pk_off);         // n*64 (12.8 MB)

    const int nsb = (E + 4095) / 4096;    // 391 scatter blocks
    const int ntb = (n + 63) / 64;        // 782 transform blocks

    k_init<<<1, 1024, 0, stream>>>(bcur);
    k_front<<<nsb + ntb + 1, 256, 0, stream>>>(ei, ew, bcur, erec, E,
                                               mean, stdv, Wm_mu, Ws_mu, pk, n,
                                               nsb, ntb, Wm_ls, Ws_ls, okl);
    k_sub_agg<<<NBC * 2, 256, 0, stream>>>(bcur, erec, pk, bm, bs, om, os, n);
}